// Round 1
// baseline (301.640 us; speedup 1.0000x reference)
//
#include <hip/hip_runtime.h>

// Geometry is fixed by the reference.
constexpr int Dd  = 96;
constexpr int Hh  = 160;
constexpr int Ww  = 160;
constexpr int HW  = Hh * Ww;       // 25600
constexpr int DHW = Dd * HW;       // 2,457,600

// Unnormalization scale factors (normalize uses /(s-1), grid_sample uses
// align_corners=False): v_sample = v_voxel * s/(s-1) - 0.5
__device__ __forceinline__ float remap_z(float v) { return v * ((float)Dd / (float)(Dd - 1)) - 0.5f; }
__device__ __forceinline__ float remap_y(float v) { return v * ((float)Hh / (float)(Hh - 1)) - 0.5f; }
__device__ __forceinline__ float remap_x(float v) { return v * ((float)Ww / (float)(Ww - 1)) - 0.5f; }

// Compute the 8 corner offsets + weights (zeros padding: weight zeroed when
// the corner is out of bounds; index clamped so the load is always in-range).
__device__ __forceinline__ void tri_setup(float x, float y, float z,
                                          int off[8], float wgt[8]) {
    float xf = floorf(x), yf = floorf(y), zf = floorf(z);
    float tx = x - xf, ty = y - yf, tz = z - zf;
    int x0 = (int)xf, y0 = (int)yf, z0 = (int)zf;
    float wx[2] = {1.0f - tx, tx};
    float wy[2] = {1.0f - ty, ty};
    float wz[2] = {1.0f - tz, tz};
    int k = 0;
#pragma unroll
    for (int dz = 0; dz < 2; ++dz) {
        int zi = z0 + dz;
        bool vz = (zi >= 0) && (zi < Dd);
        int zc = min(max(zi, 0), Dd - 1);
#pragma unroll
        for (int dy = 0; dy < 2; ++dy) {
            int yi = y0 + dy;
            bool vy = (yi >= 0) && (yi < Hh);
            int yc = min(max(yi, 0), Hh - 1);
#pragma unroll
            for (int dx = 0; dx < 2; ++dx) {
                int xi = x0 + dx;
                bool vx = (xi >= 0) && (xi < Ww);
                int xc = min(max(xi, 0), Ww - 1);
                float w = wz[dz] * wy[dy] * wx[dx];
                wgt[k] = (vx && vy && vz) ? w : 0.0f;
                off[k] = zc * HW + yc * Ww + xc;
                ++k;
            }
        }
    }
}

// out[c] = trilinear_sample(composed[c], voxel + dvf*rf) + dvf[c], c in 0..2
__global__ __launch_bounds__(256) void warp_compose(
        const float* __restrict__ composed,   // [3, DHW]
        const float* __restrict__ dvf,        // [3, DHW]
        const float* __restrict__ rf_ptr,     // scalar
        float* __restrict__ out)              // [3, DHW]
{
    int idx = blockIdx.x * blockDim.x + threadIdx.x;
    if (idx >= DHW) return;
    float rf = *rf_ptr;

    int d = idx / HW;
    int rem = idx - d * HW;
    int h = rem / Ww;
    int w = rem - h * Ww;

    float fd = dvf[idx];
    float fh = dvf[DHW + idx];
    float fw = dvf[2 * DHW + idx];

    float z = remap_z((float)d + fd * rf);
    float y = remap_y((float)h + fh * rf);
    float x = remap_x((float)w + fw * rf);

    int off[8]; float wgt[8];
    tri_setup(x, y, z, off, wgt);

    float a0 = 0.0f, a1 = 0.0f, a2 = 0.0f;
#pragma unroll
    for (int k = 0; k < 8; ++k) {
        float wk = wgt[k];
        int o = off[k];
        a0 += wk * composed[o];
        a1 += wk * composed[DHW + o];
        a2 += wk * composed[2 * DHW + o];
    }
    out[idx]           = a0 + fd;
    out[DHW + idx]     = a1 + fh;
    out[2 * DHW + idx] = a2 + fw;
}

// out = trilinear_sample(src, voxel + composed*rf)   (single channel, no add)
__global__ __launch_bounds__(256) void warp_src(
        const float* __restrict__ src,        // [DHW]
        const float* __restrict__ composed,   // [3, DHW]
        const float* __restrict__ rf_ptr,     // scalar
        float* __restrict__ out)              // [DHW]
{
    int idx = blockIdx.x * blockDim.x + threadIdx.x;
    if (idx >= DHW) return;
    float rf = *rf_ptr;

    int d = idx / HW;
    int rem = idx - d * HW;
    int h = rem / Ww;
    int w = rem - h * Ww;

    float fd = composed[idx];
    float fh = composed[DHW + idx];
    float fw = composed[2 * DHW + idx];

    float z = remap_z((float)d + fd * rf);
    float y = remap_y((float)h + fh * rf);
    float x = remap_x((float)w + fw * rf);

    int off[8]; float wgt[8];
    tri_setup(x, y, z, off, wgt);

    float acc = 0.0f;
#pragma unroll
    for (int k = 0; k < 8; ++k) {
        acc += wgt[k] * src[off[k]];
    }
    out[idx] = acc;
}

extern "C" void kernel_launch(void* const* d_in, const int* in_sizes, int n_in,
                              void* d_out, int out_size, void* d_ws, size_t ws_size,
                              hipStream_t stream) {
    const float* src        = (const float*)d_in[0];   // [1,1,D,H,W]
    const float* flow_list  = (const float*)d_in[1];   // [3,1,3,D,H,W]
    const float* final_flow = (const float*)d_in[2];   // [1,3,D,H,W]
    const float* rf         = (const float*)d_in[3];   // scalar

    float* out_img  = (float*)d_out;          // deform_2_img: [DHW]
    float* out_flow = (float*)d_out + DHW;    // out_flow (== composed3): [3,DHW]

    float* buf0 = (float*)d_ws;               // composed1: [3,DHW]
    float* buf1 = buf0 + 3 * (size_t)DHW;     // composed2: [3,DHW]

    const float* f0 = flow_list;              // flow_list[0]
    const float* f1 = flow_list + 3 * (size_t)DHW;
    const float* f2 = flow_list + 6 * (size_t)DHW;

    dim3 block(256);
    dim3 grid((DHW + 255) / 256);

    // composed1 = warp(f0, grid(f1)) + f1
    warp_compose<<<grid, block, 0, stream>>>(f0, f1, rf, buf0);
    // composed2 = warp(composed1, grid(f2)) + f2
    warp_compose<<<grid, block, 0, stream>>>(buf0, f2, rf, buf1);
    // composed3 = out_flow = warp(composed2, grid(final)) + final
    warp_compose<<<grid, block, 0, stream>>>(buf1, final_flow, rf, out_flow);
    // deform_2_img = warp(src, grid(composed3))
    warp_src<<<grid, block, 0, stream>>>(src, out_flow, rf, out_img);
}

// Round 2
// 294.490 us; speedup vs baseline: 1.0243x; 1.0243x over previous
//
#include <hip/hip_runtime.h>

// Geometry fixed by the reference.
constexpr int Dd  = 96;
constexpr int Hh  = 160;
constexpr int Ww  = 160;
constexpr int HW  = Hh * Ww;       // 25600
constexpr int DHW = Dd * HW;       // 2,457,600  (divisible by 256: 9600 blocks)

// normalize(/(s-1)) + grid_sample(align_corners=False) collapse to:
//   v_sample = v_voxel * s/(s-1) - 0.5
__device__ __forceinline__ float remap_z(float v) { return v * ((float)Dd / (float)(Dd - 1)) - 0.5f; }
__device__ __forceinline__ float remap_y(float v) { return v * ((float)Hh / (float)(Hh - 1)) - 0.5f; }
__device__ __forceinline__ float remap_x(float v) { return v * ((float)Ww / (float)(Ww - 1)) - 0.5f; }

// 8 corner offsets + weights (zeros padding: weight zeroed when out of bounds,
// index clamped so the load is always in-range).
__device__ __forceinline__ void tri_setup(float x, float y, float z,
                                          int off[8], float wgt[8]) {
    float xf = floorf(x), yf = floorf(y), zf = floorf(z);
    float tx = x - xf, ty = y - yf, tz = z - zf;
    int x0 = (int)xf, y0 = (int)yf, z0 = (int)zf;
    float wx[2] = {1.0f - tx, tx};
    float wy[2] = {1.0f - ty, ty};
    float wz[2] = {1.0f - tz, tz};
    int k = 0;
#pragma unroll
    for (int dz = 0; dz < 2; ++dz) {
        int zi = z0 + dz;
        bool vz = (zi >= 0) && (zi < Dd);
        int zc = min(max(zi, 0), Dd - 1);
#pragma unroll
        for (int dy = 0; dy < 2; ++dy) {
            int yi = y0 + dy;
            bool vy = (yi >= 0) && (yi < Hh);
            int yc = min(max(yi, 0), Hh - 1);
#pragma unroll
            for (int dx = 0; dx < 2; ++dx) {
                int xi = x0 + dx;
                bool vx = (xi >= 0) && (xi < Ww);
                int xc = min(max(xi, 0), Ww - 1);
                float w = wz[dz] * wy[dy] * wx[dx];
                wgt[k] = (vx && vy && vz) ? w : 0.0f;
                off[k] = zc * HW + yc * Ww + xc;
                ++k;
            }
        }
    }
}

// Pack planar [3,DHW] flow into interleaved [DHW] float4 (w unused).
__global__ __launch_bounds__(256) void pack3to4(
        const float* __restrict__ f, float4* __restrict__ out)
{
    int idx = blockIdx.x * blockDim.x + threadIdx.x;
    if (idx >= DHW) return;
    out[idx] = make_float4(f[idx], f[DHW + idx], f[2 * DHW + idx], 0.0f);
}

// out = trilinear_sample(composed, voxel + dvf*rf) + dvf
// composed is interleaved float4; dvf is planar (external input layout).
// PLANAR_OUT: write 3 planar channels (final stage -> d_out); else float4.
template <bool PLANAR_OUT>
__global__ __launch_bounds__(256) void warp_compose4(
        const float4* __restrict__ composed,  // [DHW] interleaved
        const float* __restrict__ dvf,        // [3, DHW] planar
        const float* __restrict__ rf_ptr,     // scalar
        float* __restrict__ outp,             // [3, DHW] planar (if PLANAR_OUT)
        float4* __restrict__ out4)            // [DHW] interleaved (else)
{
    int idx = blockIdx.x * blockDim.x + threadIdx.x;
    if (idx >= DHW) return;
    float rf = *rf_ptr;

    int d = idx / HW;
    int rem = idx - d * HW;
    int h = rem / Ww;
    int w = rem - h * Ww;

    float fd = dvf[idx];
    float fh = dvf[DHW + idx];
    float fw = dvf[2 * DHW + idx];

    float z = remap_z((float)d + fd * rf);
    float y = remap_y((float)h + fh * rf);
    float x = remap_x((float)w + fw * rf);

    int off[8]; float wgt[8];
    tri_setup(x, y, z, off, wgt);

    float a0 = 0.0f, a1 = 0.0f, a2 = 0.0f;
#pragma unroll
    for (int k = 0; k < 8; ++k) {
        float4 v = composed[off[k]];
        float wk = wgt[k];
        a0 += wk * v.x;
        a1 += wk * v.y;
        a2 += wk * v.z;
    }
    if (PLANAR_OUT) {
        outp[idx]           = a0 + fd;
        outp[DHW + idx]     = a1 + fh;
        outp[2 * DHW + idx] = a2 + fw;
    } else {
        out4[idx] = make_float4(a0 + fd, a1 + fh, a2 + fw, 0.0f);
    }
}

// out = trilinear_sample(src, voxel + composed*rf)   (single channel)
__global__ __launch_bounds__(256) void warp_src(
        const float* __restrict__ src,        // [DHW]
        const float* __restrict__ composed,   // [3, DHW] planar
        const float* __restrict__ rf_ptr,
        float* __restrict__ out)              // [DHW]
{
    int idx = blockIdx.x * blockDim.x + threadIdx.x;
    if (idx >= DHW) return;
    float rf = *rf_ptr;

    int d = idx / HW;
    int rem = idx - d * HW;
    int h = rem / Ww;
    int w = rem - h * Ww;

    float fd = composed[idx];
    float fh = composed[DHW + idx];
    float fw = composed[2 * DHW + idx];

    float z = remap_z((float)d + fd * rf);
    float y = remap_y((float)h + fh * rf);
    float x = remap_x((float)w + fw * rf);

    int off[8]; float wgt[8];
    tri_setup(x, y, z, off, wgt);

    float acc = 0.0f;
#pragma unroll
    for (int k = 0; k < 8; ++k) {
        acc += wgt[k] * src[off[k]];
    }
    out[idx] = acc;
}

extern "C" void kernel_launch(void* const* d_in, const int* in_sizes, int n_in,
                              void* d_out, int out_size, void* d_ws, size_t ws_size,
                              hipStream_t stream) {
    const float* src        = (const float*)d_in[0];   // [1,1,D,H,W]
    const float* flow_list  = (const float*)d_in[1];   // [3,1,3,D,H,W]
    const float* final_flow = (const float*)d_in[2];   // [1,3,D,H,W]
    const float* rf         = (const float*)d_in[3];   // scalar

    float* out_img  = (float*)d_out;          // deform_2_img: [DHW]
    float* out_flow = (float*)d_out + DHW;    // out_flow (== composed3): [3,DHW]

    float4* bufA = (float4*)d_ws;             // [DHW] interleaved
    float4* bufB = bufA + DHW;                // [DHW] interleaved

    const float* f0 = flow_list;
    const float* f1 = flow_list + 3 * (size_t)DHW;
    const float* f2 = flow_list + 6 * (size_t)DHW;

    dim3 block(256);
    dim3 grid(DHW / 256);

    // bufA = interleaved(f0)
    pack3to4<<<grid, block, 0, stream>>>(f0, bufA);
    // bufB = composed1 = warp(f0, grid(f1)) + f1
    warp_compose4<false><<<grid, block, 0, stream>>>(bufA, f1, rf, nullptr, bufB);
    // bufA = composed2 = warp(composed1, grid(f2)) + f2
    warp_compose4<false><<<grid, block, 0, stream>>>(bufB, f2, rf, nullptr, bufA);
    // out_flow = composed3 = warp(composed2, grid(final)) + final   (planar)
    warp_compose4<true><<<grid, block, 0, stream>>>(bufA, final_flow, rf, out_flow, nullptr);
    // deform_2_img = warp(src, grid(composed3))
    warp_src<<<grid, block, 0, stream>>>(src, out_flow, rf, out_img);
}

// Round 3
// 278.009 us; speedup vs baseline: 1.0850x; 1.0593x over previous
//
#include <hip/hip_runtime.h>

// Geometry fixed by the reference.
constexpr int Dd  = 96;
constexpr int Hh  = 160;
constexpr int Ww  = 160;
constexpr int HW  = Hh * Ww;       // 25600
constexpr int DHW = Dd * HW;       // 2,457,600  (9600 blocks of 256)
constexpr int NBLK  = DHW / 256;   // 9600, divisible by 8
constexpr int CHUNK = NBLK / 8;    // 1200 blocks (= 12 z-slices) per XCD

// XCD-aware swizzle: hardware round-robins consecutive block ids across the 8
// XCDs; remap so XCD k processes a contiguous z-chunk -> gather corners hit
// that XCD's private 4MB L2. Bijective since NBLK % 8 == 0.
__device__ __forceinline__ int swz_block(int b) {
    return (b & 7) * CHUNK + (b >> 3);
}

// normalize(/(s-1)) + grid_sample(align_corners=False) collapse to:
//   v_sample = v_voxel * s/(s-1) - 0.5
__device__ __forceinline__ float remap_z(float v) { return v * ((float)Dd / (float)(Dd - 1)) - 0.5f; }
__device__ __forceinline__ float remap_y(float v) { return v * ((float)Hh / (float)(Hh - 1)) - 0.5f; }
__device__ __forceinline__ float remap_x(float v) { return v * ((float)Ww / (float)(Ww - 1)) - 0.5f; }

// 8 corner offsets + weights (zeros padding: weight zeroed when out of bounds,
// index clamped so the load is always in-range).
__device__ __forceinline__ void tri_setup(float x, float y, float z,
                                          int off[8], float wgt[8]) {
    float xf = floorf(x), yf = floorf(y), zf = floorf(z);
    float tx = x - xf, ty = y - yf, tz = z - zf;
    int x0 = (int)xf, y0 = (int)yf, z0 = (int)zf;
    float wx[2] = {1.0f - tx, tx};
    float wy[2] = {1.0f - ty, ty};
    float wz[2] = {1.0f - tz, tz};
    int k = 0;
#pragma unroll
    for (int dz = 0; dz < 2; ++dz) {
        int zi = z0 + dz;
        bool vz = (zi >= 0) && (zi < Dd);
        int zc = min(max(zi, 0), Dd - 1);
#pragma unroll
        for (int dy = 0; dy < 2; ++dy) {
            int yi = y0 + dy;
            bool vy = (yi >= 0) && (yi < Hh);
            int yc = min(max(yi, 0), Hh - 1);
#pragma unroll
            for (int dx = 0; dx < 2; ++dx) {
                int xi = x0 + dx;
                bool vx = (xi >= 0) && (xi < Ww);
                int xc = min(max(xi, 0), Ww - 1);
                float w = wz[dz] * wy[dy] * wx[dx];
                wgt[k] = (vx && vy && vz) ? w : 0.0f;
                off[k] = zc * HW + yc * Ww + xc;
                ++k;
            }
        }
    }
}

// Pack planar [3,DHW] flow into interleaved [DHW] float4 (w unused).
__global__ __launch_bounds__(256) void pack3to4(
        const float* __restrict__ f, float4* __restrict__ out)
{
    int idx = blockIdx.x * blockDim.x + threadIdx.x;
    out[idx] = make_float4(f[idx], f[DHW + idx], f[2 * DHW + idx], 0.0f);
}

// out4 = trilinear_sample(composed, voxel + dvf*rf) + dvf   (interleaved out)
__global__ __launch_bounds__(256) void warp_compose4(
        const float4* __restrict__ composed,  // [DHW] interleaved
        const float* __restrict__ dvf,        // [3, DHW] planar
        const float* __restrict__ rf_ptr,     // scalar
        float4* __restrict__ out4)            // [DHW] interleaved
{
    int idx = swz_block(blockIdx.x) * 256 + threadIdx.x;
    float rf = *rf_ptr;

    int d = idx / HW;
    int rem = idx - d * HW;
    int h = rem / Ww;
    int w = rem - h * Ww;

    float fd = dvf[idx];
    float fh = dvf[DHW + idx];
    float fw = dvf[2 * DHW + idx];

    float z = remap_z((float)d + fd * rf);
    float y = remap_y((float)h + fh * rf);
    float x = remap_x((float)w + fw * rf);

    int off[8]; float wgt[8];
    tri_setup(x, y, z, off, wgt);

    float a0 = 0.0f, a1 = 0.0f, a2 = 0.0f;
#pragma unroll
    for (int k = 0; k < 8; ++k) {
        float4 v = composed[off[k]];
        float wk = wgt[k];
        a0 += wk * v.x;
        a1 += wk * v.y;
        a2 += wk * v.z;
    }
    out4[idx] = make_float4(a0 + fd, a1 + fh, a2 + fw, 0.0f);
}

// Fused stage 3 + 4:
//   composed3 = trilinear_sample(composed2, voxel + final*rf) + final
//   out_flow  = composed3                              (planar, -> d_out)
//   out_img   = trilinear_sample(src, voxel + composed3*rf)
// Legal to fuse: stage 4 reads composed3 only at its own voxel.
__global__ __launch_bounds__(256) void warp_final_fused(
        const float4* __restrict__ composed2, // [DHW] interleaved
        const float* __restrict__ fflow,      // [3, DHW] planar
        const float* __restrict__ src,        // [DHW]
        const float* __restrict__ rf_ptr,
        float* __restrict__ out_flow,         // [3, DHW] planar
        float* __restrict__ out_img)          // [DHW]
{
    int idx = swz_block(blockIdx.x) * 256 + threadIdx.x;
    float rf = *rf_ptr;

    int d = idx / HW;
    int rem = idx - d * HW;
    int h = rem / Ww;
    int w = rem - h * Ww;

    float fd = fflow[idx];
    float fh = fflow[DHW + idx];
    float fw = fflow[2 * DHW + idx];

    float z = remap_z((float)d + fd * rf);
    float y = remap_y((float)h + fh * rf);
    float x = remap_x((float)w + fw * rf);

    int off[8]; float wgt[8];
    tri_setup(x, y, z, off, wgt);

    float a0 = 0.0f, a1 = 0.0f, a2 = 0.0f;
#pragma unroll
    for (int k = 0; k < 8; ++k) {
        float4 v = composed2[off[k]];
        float wk = wgt[k];
        a0 += wk * v.x;
        a1 += wk * v.y;
        a2 += wk * v.z;
    }
    float c0 = a0 + fd, c1 = a1 + fh, c2 = a2 + fw;   // composed3
    out_flow[idx]           = c0;
    out_flow[DHW + idx]     = c1;
    out_flow[2 * DHW + idx] = c2;

    // stage 4: gather src at voxel + composed3*rf
    float z2 = remap_z((float)d + c0 * rf);
    float y2 = remap_y((float)h + c1 * rf);
    float x2 = remap_x((float)w + c2 * rf);

    tri_setup(x2, y2, z2, off, wgt);
    float acc = 0.0f;
#pragma unroll
    for (int k = 0; k < 8; ++k) {
        acc += wgt[k] * src[off[k]];
    }
    out_img[idx] = acc;
}

extern "C" void kernel_launch(void* const* d_in, const int* in_sizes, int n_in,
                              void* d_out, int out_size, void* d_ws, size_t ws_size,
                              hipStream_t stream) {
    const float* src        = (const float*)d_in[0];   // [1,1,D,H,W]
    const float* flow_list  = (const float*)d_in[1];   // [3,1,3,D,H,W]
    const float* final_flow = (const float*)d_in[2];   // [1,3,D,H,W]
    const float* rf         = (const float*)d_in[3];   // scalar

    float* out_img  = (float*)d_out;          // deform_2_img: [DHW]
    float* out_flow = (float*)d_out + DHW;    // out_flow (== composed3): [3,DHW]

    float4* bufA = (float4*)d_ws;             // [DHW] interleaved
    float4* bufB = bufA + DHW;                // [DHW] interleaved

    const float* f0 = flow_list;
    const float* f1 = flow_list + 3 * (size_t)DHW;
    const float* f2 = flow_list + 6 * (size_t)DHW;

    dim3 block(256);
    dim3 grid(NBLK);

    // bufA = interleaved(f0)
    pack3to4<<<grid, block, 0, stream>>>(f0, bufA);
    // bufB = composed1 = warp(f0, grid(f1)) + f1
    warp_compose4<<<grid, block, 0, stream>>>(bufA, f1, rf, bufB);
    // bufA = composed2 = warp(composed1, grid(f2)) + f2
    warp_compose4<<<grid, block, 0, stream>>>(bufB, f2, rf, bufA);
    // out_flow = composed3 ; out_img = warp(src, grid(composed3))
    warp_final_fused<<<grid, block, 0, stream>>>(bufA, final_flow, src, rf,
                                                 out_flow, out_img);
}

// Round 4
// 276.014 us; speedup vs baseline: 1.0928x; 1.0072x over previous
//
#include <hip/hip_runtime.h>

// Geometry fixed by the reference.
constexpr int Dd  = 96;
constexpr int Hh  = 160;
constexpr int Ww  = 160;
constexpr int HW  = Hh * Ww;       // 25600
constexpr int DHW = Dd * HW;       // 2,457,600

// 3D tile per 256-thread block: (z,y,x) = 2 x 8 x 16.
// Gather footprint per block ~ (2+2)(8+2)(16+2) float4 cells ~ 11.5 KB -> fits
// the 32 KB L1, so the 8 corner loads hit L1 instead of serializing on the
// miss path.
constexpr int TZ = 2, TY = 8, TX = 16;
constexpr int NTX = Ww / TX;              // 10
constexpr int NTY = Hh / TY;              // 20
constexpr int NTZ = Dd / TZ;              // 48
constexpr int NBLK = NTX * NTY * NTZ;     // 9600 (divisible by 8)
constexpr int CHUNK = NBLK / 8;           // 1200 tiles (=12 z-slices) per XCD

// XCD-aware swizzle (bijective, NBLK % 8 == 0): XCD k gets a contiguous run
// of tiles = 12 consecutive z-slices -> gather working set ~4.9 MB ~ its L2.
__device__ __forceinline__ void decode_block(int b, int tid,
                                             int& z, int& y, int& x, int& idx) {
    int s = (b & 7) * CHUNK + (b >> 3);
    int tx = s % NTX;
    int t2 = s / NTX;
    int ty = t2 % NTY;
    int tz = t2 / NTY;
    x = tx * TX + (tid & 15);
    y = ty * TY + ((tid >> 4) & 7);
    z = tz * TZ + (tid >> 7);
    idx = z * HW + y * Ww + x;
}

// normalize(/(s-1)) + grid_sample(align_corners=False) collapse to:
//   v_sample = v_voxel * s/(s-1) - 0.5
__device__ __forceinline__ float remap_z(float v) { return v * ((float)Dd / (float)(Dd - 1)) - 0.5f; }
__device__ __forceinline__ float remap_y(float v) { return v * ((float)Hh / (float)(Hh - 1)) - 0.5f; }
__device__ __forceinline__ float remap_x(float v) { return v * ((float)Ww / (float)(Ww - 1)) - 0.5f; }

// 8 corner offsets + weights (zeros padding: weight zeroed when out of bounds,
// index clamped so the load is always in-range).
__device__ __forceinline__ void tri_setup(float x, float y, float z,
                                          int off[8], float wgt[8]) {
    float xf = floorf(x), yf = floorf(y), zf = floorf(z);
    float tx = x - xf, ty = y - yf, tz = z - zf;
    int x0 = (int)xf, y0 = (int)yf, z0 = (int)zf;
    float wx[2] = {1.0f - tx, tx};
    float wy[2] = {1.0f - ty, ty};
    float wz[2] = {1.0f - tz, tz};
    int k = 0;
#pragma unroll
    for (int dz = 0; dz < 2; ++dz) {
        int zi = z0 + dz;
        bool vz = (zi >= 0) && (zi < Dd);
        int zc = min(max(zi, 0), Dd - 1);
#pragma unroll
        for (int dy = 0; dy < 2; ++dy) {
            int yi = y0 + dy;
            bool vy = (yi >= 0) && (yi < Hh);
            int yc = min(max(yi, 0), Hh - 1);
#pragma unroll
            for (int dx = 0; dx < 2; ++dx) {
                int xi = x0 + dx;
                bool vx = (xi >= 0) && (xi < Ww);
                int xc = min(max(xi, 0), Ww - 1);
                float w = wz[dz] * wy[dy] * wx[dx];
                wgt[k] = (vx && vy && vz) ? w : 0.0f;
                off[k] = zc * HW + yc * Ww + xc;
                ++k;
            }
        }
    }
}

// Stage 1: gather PLANAR f0 directly (no pack pass), output interleaved.
//   out4 = trilinear_sample(f0, voxel + f1*rf) + f1
__global__ __launch_bounds__(256) void warp_compose_p2i(
        const float* __restrict__ f0,         // [3, DHW] planar
        const float* __restrict__ dvf,        // [3, DHW] planar
        const float* __restrict__ rf_ptr,
        float4* __restrict__ out4)            // [DHW] interleaved
{
    int z, y, x, idx;
    decode_block(blockIdx.x, threadIdx.x, z, y, x, idx);
    float rf = *rf_ptr;

    float fd = dvf[idx];
    float fh = dvf[DHW + idx];
    float fw = dvf[2 * DHW + idx];

    float zz = remap_z((float)z + fd * rf);
    float yy = remap_y((float)y + fh * rf);
    float xx = remap_x((float)x + fw * rf);

    int off[8]; float wgt[8];
    tri_setup(xx, yy, zz, off, wgt);

    float a0 = 0.0f, a1 = 0.0f, a2 = 0.0f;
#pragma unroll
    for (int k = 0; k < 8; ++k) {
        float wk = wgt[k];
        int o = off[k];
        a0 += wk * f0[o];
        a1 += wk * f0[DHW + o];
        a2 += wk * f0[2 * DHW + o];
    }
    out4[idx] = make_float4(a0 + fd, a1 + fh, a2 + fw, 0.0f);
}

// Stage 2: interleaved -> interleaved compose.
__global__ __launch_bounds__(256) void warp_compose_i2i(
        const float4* __restrict__ composed,  // [DHW] interleaved
        const float* __restrict__ dvf,        // [3, DHW] planar
        const float* __restrict__ rf_ptr,
        float4* __restrict__ out4)            // [DHW] interleaved
{
    int z, y, x, idx;
    decode_block(blockIdx.x, threadIdx.x, z, y, x, idx);
    float rf = *rf_ptr;

    float fd = dvf[idx];
    float fh = dvf[DHW + idx];
    float fw = dvf[2 * DHW + idx];

    float zz = remap_z((float)z + fd * rf);
    float yy = remap_y((float)y + fh * rf);
    float xx = remap_x((float)x + fw * rf);

    int off[8]; float wgt[8];
    tri_setup(xx, yy, zz, off, wgt);

    float a0 = 0.0f, a1 = 0.0f, a2 = 0.0f;
#pragma unroll
    for (int k = 0; k < 8; ++k) {
        float4 v = composed[off[k]];
        float wk = wgt[k];
        a0 += wk * v.x;
        a1 += wk * v.y;
        a2 += wk * v.z;
    }
    out4[idx] = make_float4(a0 + fd, a1 + fh, a2 + fw, 0.0f);
}

// Fused stages 3+4:
//   composed3 = sample(composed2, voxel + final*rf) + final  -> out_flow (planar)
//   out_img   = sample(src, voxel + composed3*rf)
__global__ __launch_bounds__(256) void warp_final_fused(
        const float4* __restrict__ composed2, // [DHW] interleaved
        const float* __restrict__ fflow,      // [3, DHW] planar
        const float* __restrict__ src,        // [DHW]
        const float* __restrict__ rf_ptr,
        float* __restrict__ out_flow,         // [3, DHW] planar
        float* __restrict__ out_img)          // [DHW]
{
    int z, y, x, idx;
    decode_block(blockIdx.x, threadIdx.x, z, y, x, idx);
    float rf = *rf_ptr;

    float fd = fflow[idx];
    float fh = fflow[DHW + idx];
    float fw = fflow[2 * DHW + idx];

    float zz = remap_z((float)z + fd * rf);
    float yy = remap_y((float)y + fh * rf);
    float xx = remap_x((float)x + fw * rf);

    int off[8]; float wgt[8];
    tri_setup(xx, yy, zz, off, wgt);

    float a0 = 0.0f, a1 = 0.0f, a2 = 0.0f;
#pragma unroll
    for (int k = 0; k < 8; ++k) {
        float4 v = composed2[off[k]];
        float wk = wgt[k];
        a0 += wk * v.x;
        a1 += wk * v.y;
        a2 += wk * v.z;
    }
    float c0 = a0 + fd, c1 = a1 + fh, c2 = a2 + fw;   // composed3
    out_flow[idx]           = c0;
    out_flow[DHW + idx]     = c1;
    out_flow[2 * DHW + idx] = c2;

    float z2 = remap_z((float)z + c0 * rf);
    float y2 = remap_y((float)y + c1 * rf);
    float x2 = remap_x((float)x + c2 * rf);

    tri_setup(x2, y2, z2, off, wgt);
    float acc = 0.0f;
#pragma unroll
    for (int k = 0; k < 8; ++k) {
        acc += wgt[k] * src[off[k]];
    }
    out_img[idx] = acc;
}

extern "C" void kernel_launch(void* const* d_in, const int* in_sizes, int n_in,
                              void* d_out, int out_size, void* d_ws, size_t ws_size,
                              hipStream_t stream) {
    const float* src        = (const float*)d_in[0];   // [1,1,D,H,W]
    const float* flow_list  = (const float*)d_in[1];   // [3,1,3,D,H,W]
    const float* final_flow = (const float*)d_in[2];   // [1,3,D,H,W]
    const float* rf         = (const float*)d_in[3];   // scalar

    float* out_img  = (float*)d_out;          // deform_2_img: [DHW]
    float* out_flow = (float*)d_out + DHW;    // out_flow (== composed3): [3,DHW]

    float4* bufA = (float4*)d_ws;             // [DHW] interleaved
    float4* bufB = bufA + DHW;                // [DHW] interleaved

    const float* f0 = flow_list;
    const float* f1 = flow_list + 3 * (size_t)DHW;
    const float* f2 = flow_list + 6 * (size_t)DHW;

    dim3 block(256);
    dim3 grid(NBLK);

    // bufB = composed1 = warp(f0, grid(f1)) + f1    (planar gather, no pack)
    warp_compose_p2i<<<grid, block, 0, stream>>>(f0, f1, rf, bufB);
    // bufA = composed2 = warp(composed1, grid(f2)) + f2
    warp_compose_i2i<<<grid, block, 0, stream>>>(bufB, f2, rf, bufA);
    // out_flow = composed3 ; out_img = warp(src, grid(composed3))
    warp_final_fused<<<grid, block, 0, stream>>>(bufA, final_flow, src, rf,
                                                 out_flow, out_img);
}